// Round 2
// baseline (785.930 us; speedup 1.0000x reference)
//
#include <hip/hip_runtime.h>

#define BB 16
#define HH 256
#define WW 256
#define CC 32
#define C1 4

__device__ __forceinline__ int dot4i8(int a, int b, int c) {
#if __has_builtin(__builtin_amdgcn_sdot4)
  return __builtin_amdgcn_sdot4(a, b, c, false);
#else
  c += (int)(signed char)(a)       * (int)(signed char)(b);
  c += (int)(signed char)(a >> 8)  * (int)(signed char)(b >> 8);
  c += (int)(signed char)(a >> 16) * (int)(signed char)(b >> 16);
  c += (int)(signed char)(a >> 24) * (int)(signed char)(b >> 24);
  return c;
#endif
}

// ---- weight quantization ----
__global__ void qw1_kernel(const float* __restrict__ w, float* __restrict__ out) {
  int i = blockIdx.x * blockDim.x + threadIdx.x;
  if (i >= 32 * 4 * 9) return;
  float k = rintf(w[i] * 128.0f);
  k = fminf(127.0f, fmaxf(-127.0f, k));
  out[i] = k * 0.0078125f;  // keep OIHW, as float k/128
}

// OIHW fp32 -> [oc][tap][ic] int8
__global__ void qw_kernel(const float* __restrict__ w, signed char* __restrict__ out) {
  int i = blockIdx.x * blockDim.x + threadIdx.x;
  if (i >= 32 * 32 * 9) return;
  int oc = i / 288;
  int rem = i - oc * 288;
  int ic = rem / 9;
  int t  = rem - ic * 9;
  int q = (int)rintf(w[i] * 128.0f);
  q = min(127, max(-127, q));
  out[(oc * 9 + t) * 32 + ic] = (signed char)q;
}

__global__ void qwfc_kernel(const float* __restrict__ w, int* __restrict__ out) {
  int i = threadIdx.x;
  if (i < 32) {
    int q = (int)rintf(w[i] * 128.0f);
    q = min(127, max(-127, q));
    out[i] = q;
  }
}

// ---- conv1: fp32 NCHW input (Cin=4) -> int8 NHWC ----
__global__ __launch_bounds__(256) void conv1_kernel(
    const float* __restrict__ x, const float* __restrict__ w1q,
    signed char* __restrict__ out) {
  __shared__ float lw[32 * 4 * 9];
  int tid = threadIdx.x;
  for (int i = tid; i < 32 * 4 * 9; i += 256) lw[i] = w1q[i];
  __syncthreads();
  int b = blockIdx.z;
  int h = blockIdx.y * 16 + (tid >> 4);
  int w = blockIdx.x * 16 + (tid & 15);

  float v[C1][3][3];
#pragma unroll
  for (int ic = 0; ic < C1; ++ic)
#pragma unroll
    for (int dy = 0; dy < 3; ++dy) {
      int yy = h + dy - 1;
#pragma unroll
      for (int dx = 0; dx < 3; ++dx) {
        int xx = w + dx - 1;
        bool ok = ((unsigned)yy < 256u) && ((unsigned)xx < 256u);
        v[ic][dy][dx] = ok ? x[(((size_t)b * C1 + ic) * HH + yy) * WW + xx] : 0.0f;
      }
    }

  int ow[8];
#pragma unroll
  for (int og = 0; og < 8; ++og) {
    int packed = 0;
#pragma unroll
    for (int oj = 0; oj < 4; ++oj) {
      int oc = og * 4 + oj;
      float acc = 0.0f;
      const float* wp = &lw[oc * 36];
#pragma unroll
      for (int ic = 0; ic < C1; ++ic)
#pragma unroll
        for (int dy = 0; dy < 3; ++dy)
#pragma unroll
          for (int dx = 0; dx < 3; ++dx)
            acc += v[ic][dy][dx] * wp[(ic * 3 + dy) * 3 + dx];
      int q = (int)rintf(acc * 128.0f);
      q = min(127, max(-127, q));
      packed |= (q & 0xff) << (8 * oj);
    }
    ow[og] = packed;
  }
  signed char* op = out + (((size_t)b * HH + h) * WW + w) * CC;
  ((int4*)op)[0] = make_int4(ow[0], ow[1], ow[2], ow[3]);
  ((int4*)op)[1] = make_int4(ow[4], ow[5], ow[6], ow[7]);
}

// ---- conv layers 2..7: int8 NHWC -> int8 NHWC, exact integer math ----
__global__ __launch_bounds__(256) void conv_i8_kernel(
    const signed char* __restrict__ in, const signed char* __restrict__ wq,
    signed char* __restrict__ out) {
  __shared__ int lw[2304];  // [oc][tap][ic/4] dwords, 9216 B
  int tid = threadIdx.x;
  const int* w32 = (const int*)wq;
  for (int i = tid; i < 2304; i += 256) lw[i] = w32[i];
  __syncthreads();
  int b = blockIdx.z;
  int h = blockIdx.y * 16 + (tid >> 4);
  int w = blockIdx.x * 16 + (tid & 15);

  int a[9][8];
#pragma unroll
  for (int dy = 0; dy < 3; ++dy) {
    int yy = h + dy - 1;
#pragma unroll
    for (int dx = 0; dx < 3; ++dx) {
      int xx = w + dx - 1;
      int t = dy * 3 + dx;
      bool ok = ((unsigned)yy < 256u) && ((unsigned)xx < 256u);
      if (ok) {
        const int4* p = (const int4*)(in + (((size_t)b * HH + yy) * WW + xx) * CC);
        int4 v0 = p[0], v1 = p[1];
        a[t][0] = v0.x; a[t][1] = v0.y; a[t][2] = v0.z; a[t][3] = v0.w;
        a[t][4] = v1.x; a[t][5] = v1.y; a[t][6] = v1.z; a[t][7] = v1.w;
      } else {
#pragma unroll
        for (int d = 0; d < 8; ++d) a[t][d] = 0;
      }
    }
  }

  int* op32 = (int*)(out + (((size_t)b * HH + h) * WW + w) * CC);
  for (int og = 0; og < 8; ++og) {  // rolled: keeps code size sane
    int acc0 = 0, acc1 = 0, acc2 = 0, acc3 = 0;
    int base = og * 4 * 72;
#pragma unroll
    for (int t = 0; t < 9; ++t) {
#pragma unroll
      for (int d = 0; d < 8; ++d) {
        int av = a[t][d];
        int wi = t * 8 + d;
        acc0 = dot4i8(av, lw[base + wi],       acc0);
        acc1 = dot4i8(av, lw[base + 72 + wi],  acc1);
        acc2 = dot4i8(av, lw[base + 144 + wi], acc2);
        acc3 = dot4i8(av, lw[base + 216 + wi], acc3);
      }
    }
    // pre-act = acc/16384 ; round(pre*128) == rne(acc/128), exact in fp32
    int q0 = (int)rintf((float)acc0 * 0.0078125f);
    int q1 = (int)rintf((float)acc1 * 0.0078125f);
    int q2 = (int)rintf((float)acc2 * 0.0078125f);
    int q3 = (int)rintf((float)acc3 * 0.0078125f);
    q0 = min(127, max(-127, q0)); q1 = min(127, max(-127, q1));
    q2 = min(127, max(-127, q2)); q3 = min(127, max(-127, q3));
    op32[og] = (q0 & 0xff) | ((q1 & 0xff) << 8) | ((q2 & 0xff) << 16) | ((q3 & 0xff) << 24);
  }
}

// ---- global max over HxW per (b,c) + quantized FC ----
__global__ __launch_bounds__(256) void maxfc_kernel(
    const signed char* __restrict__ in, const int* __restrict__ wfcq,
    float* __restrict__ out) {
  __shared__ int red[256][32];
  int b = blockIdx.x;
  int tid = threadIdx.x;
  int mx[32];
#pragma unroll
  for (int c = 0; c < 32; ++c) mx[c] = -128;
  for (int p = tid; p < HH * WW; p += 256) {
    const int4* pp = (const int4*)(in + ((size_t)b * HH * WW + p) * CC);
    int4 v0 = pp[0], v1 = pp[1];
    int vs[8] = {v0.x, v0.y, v0.z, v0.w, v1.x, v1.y, v1.z, v1.w};
#pragma unroll
    for (int d = 0; d < 8; ++d) {
      mx[d * 4 + 0] = max(mx[d * 4 + 0], (int)(signed char)(vs[d]));
      mx[d * 4 + 1] = max(mx[d * 4 + 1], (int)(signed char)(vs[d] >> 8));
      mx[d * 4 + 2] = max(mx[d * 4 + 2], (int)(signed char)(vs[d] >> 16));
      mx[d * 4 + 3] = max(mx[d * 4 + 3], (int)(signed char)(vs[d] >> 24));
    }
  }
#pragma unroll
  for (int c = 0; c < 32; ++c) red[tid][c] = mx[c];
  __syncthreads();
  if (tid < 32) {
    int m = -128;
    for (int r = 0; r < 256; ++r) m = max(m, red[r][tid]);
    red[0][tid] = m;
  }
  __syncthreads();
  if (tid == 0) {
    int acc = 0;
#pragma unroll
    for (int c = 0; c < 32; ++c) acc += red[0][c] * wfcq[c];
    // y = acc/16384 ; quant: rne(y*128)=rne(acc/128), clamp, /128
    int q = (int)rintf((float)acc * 0.0078125f);
    q = min(127, max(-127, q));
    out[b] = (float)q * 0.0078125f;
  }
}

extern "C" void kernel_launch(void* const* d_in, const int* in_sizes, int n_in,
                              void* d_out, int out_size, void* d_ws, size_t ws_size,
                              hipStream_t stream) {
  const float* x   = (const float*)d_in[0];
  const float* w1  = (const float*)d_in[1];
  const float* wfc = (const float*)d_in[8];

  char* ws = (char*)d_ws;
  const size_t ACT = (size_t)BB * HH * WW * CC;  // 33,554,432 B
  signed char* A0 = (signed char*)ws;
  signed char* A1 = (signed char*)(ws + ACT);
  float*       w1q  = (float*)(ws + 2 * ACT);
  signed char* w8q  = (signed char*)(ws + 2 * ACT + 4608);
  int*         wfcq = (int*)(ws + 2 * ACT + 4608 + 6 * 9216);

  qw1_kernel<<<5, 256, 0, stream>>>(w1, w1q);
  for (int l = 0; l < 6; ++l)
    qw_kernel<<<36, 256, 0, stream>>>((const float*)d_in[2 + l], w8q + l * 9216);
  qwfc_kernel<<<1, 64, 0, stream>>>(wfc, wfcq);

  dim3 grid(16, 16, 16);  // x: w-tile, y: h-tile, z: batch
  conv1_kernel<<<grid, 256, 0, stream>>>(x, w1q, A0);

  signed char* pin = A0;
  signed char* pout = A1;
  for (int l = 0; l < 6; ++l) {
    conv_i8_kernel<<<grid, 256, 0, stream>>>(pin, w8q + l * 9216, pout);
    signed char* t = pin; pin = pout; pout = t;
  }
  maxfc_kernel<<<16, 256, 0, stream>>>(pin, wfcq, (float*)d_out);
}

// Round 3
// 335.041 us; speedup vs baseline: 2.3458x; 2.3458x over previous
//
#include <hip/hip_runtime.h>

#define BB 16
#define HH 256
#define WW 256
#define CC 32
#define C1 4

#if __has_builtin(__builtin_amdgcn_mfma_i32_32x32x32_i8)
#define K32 1
#else
#define K32 0
#endif

typedef int i32x4 __attribute__((ext_vector_type(4)));
typedef int i32x16 __attribute__((ext_vector_type(16)));

// ---- weight quantization ----
__global__ void qw1_kernel(const float* __restrict__ w, float* __restrict__ out) {
  int i = blockIdx.x * blockDim.x + threadIdx.x;
  if (i >= 32 * 4 * 9) return;
  float k = rintf(w[i] * 128.0f);
  k = fminf(127.0f, fmaxf(-127.0f, k));
  out[i] = k * 0.0078125f;  // keep OIHW, as float k/128
}

// OIHW fp32 -> per-lane MFMA B fragments (int8), matched to the A/B k-slot map.
// K index = tap*32 + ic.
//  K32: frag[(t*64 + l)*16 + j] = q(w[oc=l&31][ic=(l>>5)*16+j][tap t])
//  K16: frag[(s*64 + l)*8  + j] = q(w[oc=l&31][ic=(s&1)*16+(l>>5)*8+j][tap s>>1])
__global__ void qw_frag_kernel(const float* __restrict__ w, signed char* __restrict__ frag) {
  int i = blockIdx.x * blockDim.x + threadIdx.x;
  if (i >= 9216) return;
#if K32
  int t = i >> 10;
  int l = (i >> 4) & 63;
  int j = i & 15;
  int ic = (l >> 5) * 16 + j;
#else
  int s = i >> 9;
  int l = (i >> 3) & 63;
  int j = i & 7;
  int t = s >> 1;
  int ic = (s & 1) * 16 + (l >> 5) * 8 + j;
#endif
  int oc = l & 31;
  int q = (int)rintf(w[oc * 288 + ic * 9 + t] * 128.0f);
  q = min(127, max(-127, q));
  frag[i] = (signed char)q;
}

__global__ void qwfc_kernel(const float* __restrict__ w, int* __restrict__ out) {
  int i = threadIdx.x;
  if (i < 32) {
    int q = (int)rintf(w[i] * 128.0f);
    q = min(127, max(-127, q));
    out[i] = q;
  }
}

// ---- conv1: fp32 NCHW input (Cin=4) -> int8 NHWC ----
__global__ __launch_bounds__(256) void conv1_kernel(
    const float* __restrict__ x, const float* __restrict__ w1q,
    signed char* __restrict__ out) {
  __shared__ float lw[32 * 4 * 9];
  int tid = threadIdx.x;
  for (int i = tid; i < 32 * 4 * 9; i += 256) lw[i] = w1q[i];
  __syncthreads();
  int b = blockIdx.z;
  int h = blockIdx.y * 16 + (tid >> 4);
  int w = blockIdx.x * 16 + (tid & 15);

  float v[C1][3][3];
#pragma unroll
  for (int ic = 0; ic < C1; ++ic)
#pragma unroll
    for (int dy = 0; dy < 3; ++dy) {
      int yy = h + dy - 1;
#pragma unroll
      for (int dx = 0; dx < 3; ++dx) {
        int xx = w + dx - 1;
        bool ok = ((unsigned)yy < 256u) && ((unsigned)xx < 256u);
        v[ic][dy][dx] = ok ? x[(((size_t)b * C1 + ic) * HH + yy) * WW + xx] : 0.0f;
      }
    }

  int ow[8];
#pragma unroll
  for (int og = 0; og < 8; ++og) {
    int packed = 0;
#pragma unroll
    for (int oj = 0; oj < 4; ++oj) {
      int oc = og * 4 + oj;
      float acc = 0.0f;
      const float* wp = &lw[oc * 36];
#pragma unroll
      for (int ic = 0; ic < C1; ++ic)
#pragma unroll
        for (int dy = 0; dy < 3; ++dy)
#pragma unroll
          for (int dx = 0; dx < 3; ++dx)
            acc += v[ic][dy][dx] * wp[(ic * 3 + dy) * 3 + dx];
      int q = (int)rintf(acc * 128.0f);
      q = min(127, max(-127, q));
      packed |= (q & 0xff) << (8 * oj);
    }
    ow[og] = packed;
  }
  signed char* op = out + (((size_t)b * HH + h) * WW + w) * CC;
  ((int4*)op)[0] = make_int4(ow[0], ow[1], ow[2], ow[3]);
  ((int4*)op)[1] = make_int4(ow[4], ow[5], ow[6], ow[7]);
}

// ---- conv layers 2..7: implicit-GEMM via i8 MFMA ----
// Wave tile: M=32 consecutive pixels (one h row), N=32 oc, K=288.
// A fragment = direct NHWC global load (16B or 8B per lane); B in registers.
__global__ __launch_bounds__(256) void conv_mfma_kernel(
    const signed char* __restrict__ in, const signed char* __restrict__ frag,
    signed char* __restrict__ out) {
  int tid = threadIdx.x;
  int wi = tid >> 6;
  int l = tid & 63;
  int lo = l & 31;
  int hi = l >> 5;
  int b = blockIdx.z;
  int h = blockIdx.y;
  int wbase = blockIdx.x * 128 + wi * 32;
  int w = wbase + lo;  // this lane's GEMM row (pixel column)

  i32x16 acc = {};
  const size_t img = (size_t)b * (HH * WW);

#if K32
  i32x4 bf[9];
  const i32x4* fp = (const i32x4*)frag;
#pragma unroll
  for (int s = 0; s < 9; ++s) bf[s] = fp[s * 64 + l];

#pragma unroll
  for (int t = 0; t < 9; ++t) {
    int dy = t / 3, dx = t % 3;
    int yy = h + dy - 1;
    int xx = w + dx - 1;
    i32x4 av = {};
    if (((unsigned)yy < 256u) && ((unsigned)xx < 256u))
      av = *(const i32x4*)(in + ((img + (size_t)yy * WW + xx) << 5) + hi * 16);
    acc = __builtin_amdgcn_mfma_i32_32x32x32_i8(av, bf[t], acc, 0, 0, 0);
  }
#else
  long bf[18];
  const long* fp = (const long*)frag;
#pragma unroll
  for (int s = 0; s < 18; ++s) bf[s] = fp[s * 64 + l];

#pragma unroll
  for (int s = 0; s < 18; ++s) {
    int t = s >> 1;
    int dy = t / 3, dx = t % 3;
    int yy = h + dy - 1;
    int xx = w + dx - 1;
    long av = 0;
    if (((unsigned)yy < 256u) && ((unsigned)xx < 256u))
      av = *(const long*)(in + ((img + (size_t)yy * WW + xx) << 5) + (s & 1) * 16 + hi * 8);
    acc = __builtin_amdgcn_mfma_i32_32x32x16_i8(av, bf[s], acc, 0, 0, 0);
  }
#endif

  // C/D: col(oc) = lane&31, row(pixel) = (r&3) + 8*(r>>2) + 4*(lane>>5)
  signed char* op = out + ((img + (size_t)h * WW + wbase) << 5) + lo;
#pragma unroll
  for (int r = 0; r < 16; ++r) {
    int row = (r & 3) + 8 * (r >> 2) + 4 * hi;
    int q = (int)rintf((float)acc[r] * 0.0078125f);  // rne(acc/128), exact
    q = min(127, max(-127, q));
    op[row * 32] = (signed char)q;
  }
}

// ---- global max over HxW per (b,c) + quantized FC ----
__global__ __launch_bounds__(256) void maxfc_kernel(
    const signed char* __restrict__ in, const int* __restrict__ wfcq,
    float* __restrict__ out) {
  __shared__ int red[256][32];
  int b = blockIdx.x;
  int tid = threadIdx.x;
  int mx[32];
#pragma unroll
  for (int c = 0; c < 32; ++c) mx[c] = -128;
  for (int p = tid; p < HH * WW; p += 256) {
    const int4* pp = (const int4*)(in + ((size_t)b * HH * WW + p) * CC);
    int4 v0 = pp[0], v1 = pp[1];
    int vs[8] = {v0.x, v0.y, v0.z, v0.w, v1.x, v1.y, v1.z, v1.w};
#pragma unroll
    for (int d = 0; d < 8; ++d) {
      mx[d * 4 + 0] = max(mx[d * 4 + 0], (int)(signed char)(vs[d]));
      mx[d * 4 + 1] = max(mx[d * 4 + 1], (int)(signed char)(vs[d] >> 8));
      mx[d * 4 + 2] = max(mx[d * 4 + 2], (int)(signed char)(vs[d] >> 16));
      mx[d * 4 + 3] = max(mx[d * 4 + 3], (int)(signed char)(vs[d] >> 24));
    }
  }
#pragma unroll
  for (int c = 0; c < 32; ++c) red[tid][c] = mx[c];
  __syncthreads();
  if (tid < 32) {
    int m = -128;
    for (int r = 0; r < 256; ++r) m = max(m, red[r][tid]);
    red[0][tid] = m;
  }
  __syncthreads();
  if (tid == 0) {
    int acc = 0;
#pragma unroll
    for (int c = 0; c < 32; ++c) acc += red[0][c] * wfcq[c];
    int q = (int)rintf((float)acc * 0.0078125f);
    q = min(127, max(-127, q));
    out[b] = (float)q * 0.0078125f;
  }
}

extern "C" void kernel_launch(void* const* d_in, const int* in_sizes, int n_in,
                              void* d_out, int out_size, void* d_ws, size_t ws_size,
                              hipStream_t stream) {
  const float* x   = (const float*)d_in[0];
  const float* w1  = (const float*)d_in[1];
  const float* wfc = (const float*)d_in[8];

  char* ws = (char*)d_ws;
  const size_t ACT = (size_t)BB * HH * WW * CC;  // 33,554,432 B
  signed char* A0   = (signed char*)ws;
  signed char* A1   = (signed char*)(ws + ACT);
  float*       w1q  = (float*)(ws + 2 * ACT);
  signed char* wfr  = (signed char*)(ws + 2 * ACT + 4608);        // 6 x 9216
  int*         wfcq = (int*)(ws + 2 * ACT + 4608 + 6 * 9216);

  qw1_kernel<<<5, 256, 0, stream>>>(w1, w1q);
  for (int l = 0; l < 6; ++l)
    qw_frag_kernel<<<36, 256, 0, stream>>>((const float*)d_in[2 + l], wfr + l * 9216);
  qwfc_kernel<<<1, 64, 0, stream>>>(wfc, wfcq);

  dim3 grid1(16, 16, 16);
  conv1_kernel<<<grid1, 256, 0, stream>>>(x, w1q, A0);

  dim3 gridc(2, 256, 16);  // x: 128-pixel strip, y: h, z: batch
  signed char* pin = A0;
  signed char* pout = A1;
  for (int l = 0; l < 6; ++l) {
    conv_mfma_kernel<<<gridc, 256, 0, stream>>>(pin, wfr + l * 9216, pout);
    signed char* t = pin; pin = pout; pout = t;
  }
  maxfc_kernel<<<16, 256, 0, stream>>>(pin, wfcq, (float*)d_out);
}

// Round 4
// 264.204 us; speedup vs baseline: 2.9747x; 1.2681x over previous
//
#include <hip/hip_runtime.h>

#define BB 16
#define HH 256
#define WW 256
#define CC 32
#define C1 4

#if __has_builtin(__builtin_amdgcn_mfma_i32_32x32x32_i8)
#define K32 1
#else
#define K32 0
#endif

typedef int i32x4 __attribute__((ext_vector_type(4)));
typedef int i32x16 __attribute__((ext_vector_type(16)));

// ---- weight quantization ----
__global__ void qw1_kernel(const float* __restrict__ w, float* __restrict__ out) {
  int i = blockIdx.x * blockDim.x + threadIdx.x;
  if (i >= 32 * 4 * 9) return;
  float k = rintf(w[i] * 128.0f);
  k = fminf(127.0f, fmaxf(-127.0f, k));
  out[i] = k * 0.0078125f;  // keep OIHW, as float k/128
}

// OIHW fp32 -> per-lane MFMA B fragments (int8), matched to the A/B k-slot map.
__global__ void qw_frag_kernel(const float* __restrict__ w, signed char* __restrict__ frag) {
  int i = blockIdx.x * blockDim.x + threadIdx.x;
  if (i >= 9216) return;
#if K32
  int t = i >> 10;
  int l = (i >> 4) & 63;
  int j = i & 15;
  int ic = (l >> 5) * 16 + j;
#else
  int s = i >> 9;
  int l = (i >> 3) & 63;
  int j = i & 7;
  int t = s >> 1;
  int ic = (s & 1) * 16 + (l >> 5) * 8 + j;
#endif
  int oc = l & 31;
  int q = (int)rintf(w[oc * 288 + ic * 9 + t] * 128.0f);
  q = min(127, max(-127, q));
  frag[i] = (signed char)q;
}

__global__ void qwfc_kernel(const float* __restrict__ w, int* __restrict__ out) {
  int i = threadIdx.x;
  if (i < 32) {
    int q = (int)rintf(w[i] * 128.0f);
    q = min(127, max(-127, q));
    out[i] = q;
  }
}

__global__ void initmax_kernel(int* __restrict__ gmax) {
  int i = threadIdx.x;
  if (i < 512) gmax[i] = -128;
}

// ---- conv1: fp32 NCHW input (Cin=4) -> int8 NHWC ----
__global__ __launch_bounds__(256) void conv1_kernel(
    const float* __restrict__ x, const float* __restrict__ w1q,
    signed char* __restrict__ out) {
  __shared__ float lw[32 * 4 * 9];
  int tid = threadIdx.x;
  for (int i = tid; i < 32 * 4 * 9; i += 256) lw[i] = w1q[i];
  __syncthreads();
  int b = blockIdx.z;
  int h = blockIdx.y * 16 + (tid >> 4);
  int w = blockIdx.x * 16 + (tid & 15);

  float v[C1][3][3];
#pragma unroll
  for (int ic = 0; ic < C1; ++ic)
#pragma unroll
    for (int dy = 0; dy < 3; ++dy) {
      int yy = h + dy - 1;
#pragma unroll
      for (int dx = 0; dx < 3; ++dx) {
        int xx = w + dx - 1;
        bool ok = ((unsigned)yy < 256u) && ((unsigned)xx < 256u);
        v[ic][dy][dx] = ok ? x[(((size_t)b * C1 + ic) * HH + yy) * WW + xx] : 0.0f;
      }
    }

  int ow[8];
#pragma unroll
  for (int og = 0; og < 8; ++og) {
    int packed = 0;
#pragma unroll
    for (int oj = 0; oj < 4; ++oj) {
      int oc = og * 4 + oj;
      float acc = 0.0f;
      const float* wp = &lw[oc * 36];
#pragma unroll
      for (int ic = 0; ic < C1; ++ic)
#pragma unroll
        for (int dy = 0; dy < 3; ++dy)
#pragma unroll
          for (int dx = 0; dx < 3; ++dx)
            acc += v[ic][dy][dx] * wp[(ic * 3 + dy) * 3 + dx];
      int q = (int)rintf(acc * 128.0f);
      q = min(127, max(-127, q));
      packed |= (q & 0xff) << (8 * oj);
    }
    ow[og] = packed;
  }
  signed char* op = out + (((size_t)b * HH + h) * WW + w) * CC;
  ((int4*)op)[0] = make_int4(ow[0], ow[1], ow[2], ow[3]);
  ((int4*)op)[1] = make_int4(ow[4], ow[5], ow[6], ow[7]);
}

// ---- MFMA conv body shared by mid/last variants ----
__device__ __forceinline__ i32x16 conv_mfma_body(
    const signed char* __restrict__ in, const signed char* __restrict__ frag,
    int b, int h, int w, int l, int hi) {
  i32x16 acc = {};
  const size_t img = (size_t)b * (HH * WW);
#if K32
  i32x4 bf[9];
  const i32x4* fp = (const i32x4*)frag;
#pragma unroll
  for (int s = 0; s < 9; ++s) bf[s] = fp[s * 64 + l];
#pragma unroll
  for (int t = 0; t < 9; ++t) {
    int dy = t / 3, dx = t % 3;
    int yy = h + dy - 1;
    int xx = w + dx - 1;
    i32x4 av = {};
    if (((unsigned)yy < 256u) && ((unsigned)xx < 256u))
      av = *(const i32x4*)(in + ((img + (size_t)yy * WW + xx) << 5) + hi * 16);
    acc = __builtin_amdgcn_mfma_i32_32x32x32_i8(av, bf[t], acc, 0, 0, 0);
  }
#else
  long bf[18];
  const long* fp = (const long*)frag;
#pragma unroll
  for (int s = 0; s < 18; ++s) bf[s] = fp[s * 64 + l];
#pragma unroll
  for (int s = 0; s < 18; ++s) {
    int t = s >> 1;
    int dy = t / 3, dx = t % 3;
    int yy = h + dy - 1;
    int xx = w + dx - 1;
    long av = 0;
    if (((unsigned)yy < 256u) && ((unsigned)xx < 256u))
      av = *(const long*)(in + ((img + (size_t)yy * WW + xx) << 5) + (s & 1) * 16 + hi * 8);
    acc = __builtin_amdgcn_mfma_i32_32x32x16_i8(av, bf[s], acc, 0, 0, 0);
  }
#endif
  return acc;
}

// ---- conv layers 2..6: implicit-GEMM via i8 MFMA, writes int8 NHWC ----
__global__ __launch_bounds__(256) void conv_mfma_kernel(
    const signed char* __restrict__ in, const signed char* __restrict__ frag,
    signed char* __restrict__ out) {
  int tid = threadIdx.x;
  int wi = tid >> 6;
  int l = tid & 63;
  int lo = l & 31;
  int hi = l >> 5;
  int b = blockIdx.z;
  int h = blockIdx.y;
  int wbase = blockIdx.x * 128 + wi * 32;

  i32x16 acc = conv_mfma_body(in, frag, b, h, wbase + lo, l, hi);

  // C/D: col(oc) = lane&31, row(pixel) = (r&3) + 8*(r>>2) + 4*(lane>>5)
  signed char* op = out + (((size_t)b * (HH * WW) + (size_t)h * WW + wbase) << 5) + lo;
#pragma unroll
  for (int r = 0; r < 16; ++r) {
    int row = (r & 3) + 8 * (r >> 2) + 4 * hi;
    int q = (int)rintf((float)acc[r] * 0.0078125f);  // rne(acc/128), exact
    q = min(127, max(-127, q));
    op[row * 32] = (signed char)q;
  }
}

// ---- conv layer 7: same math, no activation store; fused global-max ----
__global__ __launch_bounds__(256) void conv_mfma_last_kernel(
    const signed char* __restrict__ in, const signed char* __restrict__ frag,
    int* __restrict__ gmax) {
  __shared__ int red[4][32];
  int tid = threadIdx.x;
  int wi = tid >> 6;
  int l = tid & 63;
  int lo = l & 31;
  int hi = l >> 5;
  int b = blockIdx.z;
  int h = blockIdx.y;
  int wbase = blockIdx.x * 128 + wi * 32;

  i32x16 acc = conv_mfma_body(in, frag, b, h, wbase + lo, l, hi);

  int mymax = -128;
#pragma unroll
  for (int r = 0; r < 16; ++r) {
    int q = (int)rintf((float)acc[r] * 0.0078125f);
    q = min(127, max(-127, q));
    mymax = max(mymax, q);
  }
  // combine the two lane-halves (same oc, complementary pixel rows)
  mymax = max(mymax, __shfl_xor(mymax, 32));
  if (hi == 0) red[wi][lo] = mymax;
  __syncthreads();
  if (tid < 32) {
    int m = max(max(red[0][tid], red[1][tid]), max(red[2][tid], red[3][tid]));
    atomicMax(&gmax[b * 32 + tid], m);
  }
}

// ---- final FC over per-(b,oc) maxes ----
__global__ void fc_kernel(const int* __restrict__ gmax, const int* __restrict__ wfcq,
                          float* __restrict__ out) {
  int b = threadIdx.x;
  if (b < BB) {
    int acc = 0;
#pragma unroll
    for (int c = 0; c < 32; ++c) acc += gmax[b * 32 + c] * wfcq[c];
    int q = (int)rintf((float)acc * 0.0078125f);  // rne(acc/128), exact
    q = min(127, max(-127, q));
    out[b] = (float)q * 0.0078125f;
  }
}

extern "C" void kernel_launch(void* const* d_in, const int* in_sizes, int n_in,
                              void* d_out, int out_size, void* d_ws, size_t ws_size,
                              hipStream_t stream) {
  const float* x   = (const float*)d_in[0];
  const float* w1  = (const float*)d_in[1];
  const float* wfc = (const float*)d_in[8];

  char* ws = (char*)d_ws;
  const size_t ACT = (size_t)BB * HH * WW * CC;  // 33,554,432 B
  signed char* A0   = (signed char*)ws;
  signed char* A1   = (signed char*)(ws + ACT);
  float*       w1q  = (float*)(ws + 2 * ACT);
  signed char* wfr  = (signed char*)(ws + 2 * ACT + 4608);        // 6 x 9216
  int*         wfcq = (int*)(ws + 2 * ACT + 4608 + 6 * 9216);
  int*         gmax = (int*)(ws + 2 * ACT + 4608 + 6 * 9216 + 128);

  qw1_kernel<<<5, 256, 0, stream>>>(w1, w1q);
  for (int l = 0; l < 6; ++l)
    qw_frag_kernel<<<36, 256, 0, stream>>>((const float*)d_in[2 + l], wfr + l * 9216);
  qwfc_kernel<<<1, 64, 0, stream>>>(wfc, wfcq);
  initmax_kernel<<<1, 512, 0, stream>>>(gmax);

  dim3 grid1(16, 16, 16);
  conv1_kernel<<<grid1, 256, 0, stream>>>(x, w1q, A0);

  dim3 gridc(2, 256, 16);  // x: 128-pixel strip, y: h, z: batch
  signed char* pin = A0;
  signed char* pout = A1;
  for (int l = 0; l < 5; ++l) {
    conv_mfma_kernel<<<gridc, 256, 0, stream>>>(pin, wfr + l * 9216, pout);
    signed char* t = pin; pin = pout; pout = t;
  }
  conv_mfma_last_kernel<<<gridc, 256, 0, stream>>>(pin, wfr + 5 * 9216, gmax);
  fc_kernel<<<1, 64, 0, stream>>>(gmax, wfcq, (float*)d_out);
}

// Round 6
// 226.777 us; speedup vs baseline: 3.4656x; 1.1650x over previous
//
#include <hip/hip_runtime.h>

#define BB 16
#define HH 256
#define WW 256
#define CC 32
#define C1 4

#if __has_builtin(__builtin_amdgcn_mfma_i32_32x32x32_i8)
#define K32 1
#else
#define K32 0
#endif

typedef int i32x4 __attribute__((ext_vector_type(4)));
typedef int i32x16 __attribute__((ext_vector_type(16)));

// ---- weight quantization ----
__global__ void qw1_kernel(const float* __restrict__ w, float* __restrict__ out) {
  int i = blockIdx.x * blockDim.x + threadIdx.x;
  if (i >= 32 * 4 * 9) return;
  float k = rintf(w[i] * 128.0f);
  k = fminf(127.0f, fmaxf(-127.0f, k));
  out[i] = k * 0.0078125f;  // keep OIHW, as float k/128
}

// OIHW fp32 -> per-lane MFMA B fragments (int8), matched to the A/B k-slot map.
__global__ void qw_frag_kernel(const float* __restrict__ w, signed char* __restrict__ frag) {
  int i = blockIdx.x * blockDim.x + threadIdx.x;
  if (i >= 9216) return;
#if K32
  int t = i >> 10;
  int l = (i >> 4) & 63;
  int j = i & 15;
  int ic = (l >> 5) * 16 + j;
#else
  int s = i >> 9;
  int l = (i >> 3) & 63;
  int j = i & 7;
  int t = s >> 1;
  int ic = (s & 1) * 16 + (l >> 5) * 8 + j;
#endif
  int oc = l & 31;
  int q = (int)rintf(w[oc * 288 + ic * 9 + t] * 128.0f);
  q = min(127, max(-127, q));
  frag[i] = (signed char)q;
}

__global__ void qwfc_kernel(const float* __restrict__ w, int* __restrict__ out) {
  int i = threadIdx.x;
  if (i < 32) {
    int q = (int)rintf(w[i] * 128.0f);
    q = min(127, max(-127, q));
    out[i] = q;
  }
}

__global__ void initmax_kernel(int* __restrict__ gmax) {
  int i = threadIdx.x;
  if (i < 512) gmax[i] = -128;
}

// ---- conv1: fp32 NCHW input (Cin=4) -> int8 NHWC ----
// Weights read via wave-uniform global indices -> compiler scalarizes to
// s_load + SGPR operand in v_fmac (no LDS, no per-lane weight traffic).
__global__ __launch_bounds__(256) void conv1_kernel(
    const float* __restrict__ x, const float* __restrict__ w1q,
    signed char* __restrict__ out) {
  int tid = threadIdx.x;
  int b = blockIdx.z;
  int h = blockIdx.y * 16 + (tid >> 4);
  int w = blockIdx.x * 16 + (tid & 15);

  float v[36];
#pragma unroll
  for (int ic = 0; ic < C1; ++ic)
#pragma unroll
    for (int dy = 0; dy < 3; ++dy) {
      int yy = h + dy - 1;
#pragma unroll
      for (int dx = 0; dx < 3; ++dx) {
        int xx = w + dx - 1;
        bool ok = ((unsigned)yy < 256u) && ((unsigned)xx < 256u);
        v[ic * 9 + dy * 3 + dx] = ok ? x[(((size_t)b * C1 + ic) * HH + yy) * WW + xx] : 0.0f;
      }
    }

  int ow[8];
#pragma unroll
  for (int og = 0; og < 8; ++og) {
    int packed = 0;
#pragma unroll
    for (int oj = 0; oj < 4; ++oj) {
      int oc = og * 4 + oj;
      float acc = 0.0f;
      const float* wp = &w1q[oc * 36];
#pragma unroll
      for (int i = 0; i < 36; ++i) acc += v[i] * wp[i];  // same order as reference
      int q = (int)rintf(acc * 128.0f);
      q = min(127, max(-127, q));
      packed |= (q & 0xff) << (8 * oj);
    }
    ow[og] = packed;
  }
  signed char* op = out + (((size_t)b * HH + h) * WW + w) * CC;
  ((int4*)op)[0] = make_int4(ow[0], ow[1], ow[2], ow[3]);
  ((int4*)op)[1] = make_int4(ow[4], ow[5], ow[6], ow[7]);
}

__device__ __forceinline__ void quant_store(const i32x16& acc, signed char* op, int hi) {
#pragma unroll
  for (int r = 0; r < 16; ++r) {
    int row = (r & 3) + 8 * (r >> 2) + 4 * hi;
    int q = (int)rintf((float)acc[r] * 0.0078125f);  // rne(acc/128), exact
    q = min(127, max(-127, q));
    op[row * 32] = (signed char)q;
  }
}

__device__ __forceinline__ int quant_max(const i32x16& acc, int mymax) {
#pragma unroll
  for (int r = 0; r < 16; ++r) {
    int q = (int)rintf((float)acc[r] * 0.0078125f);
    q = min(127, max(-127, q));
    mymax = max(mymax, q);
  }
  return mymax;
}

// ---- conv layers 2..7: implicit-GEMM via i8 MFMA, 2 output rows per wave ----
// Wave tile: M = 32 px x 2 rows, N = 32 oc, K = 288. The 4 input rows are
// shared between the two output rows: 12 tap-loads for 18 MFMAs.
template <bool LAST>
__global__ __launch_bounds__(256) void conv_mfma_kernel_t(
    const signed char* __restrict__ in, const signed char* __restrict__ frag,
    signed char* __restrict__ out, int* __restrict__ gmax) {
  __shared__ int red[4][32];
  int tid = threadIdx.x;
  int wi = tid >> 6;
  int l = tid & 63;
  int lo = l & 31;
  int hi = l >> 5;
  int b = blockIdx.z;
  int h0 = blockIdx.y * 2;  // output rows h0, h0+1
  int wbase = blockIdx.x * 128 + wi * 32;
  int w = wbase + lo;

  const size_t img = (size_t)b * (HH * WW);
  i32x16 acc0 = {}, acc1 = {};

#if K32
  i32x4 bf[9];
  const i32x4* fp = (const i32x4*)frag;
#pragma unroll
  for (int s = 0; s < 9; ++s) bf[s] = fp[s * 64 + l];

#pragma unroll
  for (int row = 0; row < 4; ++row) {  // input rows h0-1 .. h0+2
    int yy = h0 - 1 + row;
    bool okrow = (unsigned)yy < 256u;
#pragma unroll
    for (int dx = 0; dx < 3; ++dx) {
      int xx = w + dx - 1;
      i32x4 av = {};
      if (okrow && ((unsigned)xx < 256u))
        av = *(const i32x4*)(in + ((img + (size_t)yy * WW + xx) << 5) + hi * 16);
      if (row < 3) acc0 = __builtin_amdgcn_mfma_i32_32x32x32_i8(av, bf[row * 3 + dx], acc0, 0, 0, 0);
      if (row > 0) acc1 = __builtin_amdgcn_mfma_i32_32x32x32_i8(av, bf[(row - 1) * 3 + dx], acc1, 0, 0, 0);
    }
  }
#else
  long bf[18];
  const long* fp = (const long*)frag;
#pragma unroll
  for (int s = 0; s < 18; ++s) bf[s] = fp[s * 64 + l];

#pragma unroll
  for (int row = 0; row < 4; ++row) {
    int yy = h0 - 1 + row;
    bool okrow = (unsigned)yy < 256u;
#pragma unroll
    for (int dx = 0; dx < 3; ++dx) {
      int xx = w + dx - 1;
#pragma unroll
      for (int s2 = 0; s2 < 2; ++s2) {
        long av = 0;
        if (okrow && ((unsigned)xx < 256u))
          av = *(const long*)(in + ((img + (size_t)yy * WW + xx) << 5) + s2 * 16 + hi * 8);
        if (row < 3)
          acc0 = __builtin_amdgcn_mfma_i32_32x32x16_i8(av, bf[(row * 3 + dx) * 2 + s2], acc0, 0, 0, 0);
        if (row > 0)
          acc1 = __builtin_amdgcn_mfma_i32_32x32x16_i8(av, bf[((row - 1) * 3 + dx) * 2 + s2], acc1, 0, 0, 0);
      }
    }
  }
#endif

  if (!LAST) {
    signed char* op0 = out + ((img + (size_t)h0 * WW + wbase) << 5) + lo;
    quant_store(acc0, op0, hi);
    quant_store(acc1, op0 + ((size_t)WW << 5), hi);
  } else {
    int mymax = quant_max(acc1, quant_max(acc0, -128));
    mymax = max(mymax, __shfl_xor(mymax, 32));
    if (hi == 0) red[wi][lo] = mymax;
    __syncthreads();
    if (tid < 32) {
      int m = max(max(red[0][tid], red[1][tid]), max(red[2][tid], red[3][tid]));
      atomicMax(&gmax[b * 32 + tid], m);
    }
  }
}

// ---- final FC over per-(b,oc) maxes ----
__global__ void fc_kernel(const int* __restrict__ gmax, const int* __restrict__ wfcq,
                          float* __restrict__ out) {
  int b = threadIdx.x;
  if (b < BB) {
    int acc = 0;
#pragma unroll
    for (int c = 0; c < 32; ++c) acc += gmax[b * 32 + c] * wfcq[c];
    int q = (int)rintf((float)acc * 0.0078125f);  // rne(acc/128), exact
    q = min(127, max(-127, q));
    out[b] = (float)q * 0.0078125f;
  }
}

extern "C" void kernel_launch(void* const* d_in, const int* in_sizes, int n_in,
                              void* d_out, int out_size, void* d_ws, size_t ws_size,
                              hipStream_t stream) {
  const float* x   = (const float*)d_in[0];
  const float* w1  = (const float*)d_in[1];
  const float* wfc = (const float*)d_in[8];

  char* ws = (char*)d_ws;
  const size_t ACT = (size_t)BB * HH * WW * CC;  // 33,554,432 B
  signed char* A0   = (signed char*)ws;
  signed char* A1   = (signed char*)(ws + ACT);
  float*       w1q  = (float*)(ws + 2 * ACT);
  signed char* wfr  = (signed char*)(ws + 2 * ACT + 4608);        // 6 x 9216
  int*         wfcq = (int*)(ws + 2 * ACT + 4608 + 6 * 9216);
  int*         gmax = (int*)(ws + 2 * ACT + 4608 + 6 * 9216 + 128);

  qw1_kernel<<<5, 256, 0, stream>>>(w1, w1q);
  for (int l = 0; l < 6; ++l)
    qw_frag_kernel<<<36, 256, 0, stream>>>((const float*)d_in[2 + l], wfr + l * 9216);
  qwfc_kernel<<<1, 64, 0, stream>>>(wfc, wfcq);
  initmax_kernel<<<1, 512, 0, stream>>>(gmax);

  dim3 grid1(16, 16, 16);
  conv1_kernel<<<grid1, 256, 0, stream>>>(x, w1q, A0);

  dim3 gridc(2, 128, 16);  // x: 128-px strip, y: 2-row pair, z: batch
  signed char* pin = A0;
  signed char* pout = A1;
  for (int l = 0; l < 5; ++l) {
    conv_mfma_kernel_t<false><<<gridc, 256, 0, stream>>>(pin, wfr + l * 9216, pout, nullptr);
    signed char* t = pin; pin = pout; pout = t;
  }
  conv_mfma_kernel_t<true><<<gridc, 256, 0, stream>>>(pin, wfr + 5 * 9216, nullptr, gmax);
  fc_kernel<<<1, 64, 0, stream>>>(gmax, wfcq, (float*)d_out);
}